// Round 13
// baseline (212.545 us; speedup 1.0000x reference)
//
#include <hip/hip_runtime.h>
#include <hip/hip_bf16.h>

#define V_SIZE 32000
#define SEQ 64
#define BATCH 64
#define EMB 32
#define HID 16
#define NROWS (SEQ * BATCH)   // 4096
#define V4 (V_SIZE / 4)       // 8000 float4 columns
#define STRIPS 32             // k_write: 32 strips * 256 f4-cols
#define CHUNKS 64
#define ROWS_W (NROWS / CHUNKS)   // 64 rows per chunk
#define RGROUP 8                  // rows per inner group in k_write
#define NRB (NROWS / 16)          // 256 row-blocks (MFMA M-tiles)
#define NTILES (V_SIZE / 16)      // 2000 col-tiles (MFMA N-tiles)
#define XSTRIPS 50                // expsum strips
#define TPW (NTILES / XSTRIPS)    // 40 tiles per wave
#define NSLOTS XSTRIPS
#define XREPS 3                   // DIAGNOSTIC: internal repeat so expsum tops profile

typedef float f32x4 __attribute__((ext_vector_type(4)));
typedef short short8 __attribute__((ext_vector_type(8)));

__device__ inline short bf16_rne(float x) {
    unsigned u = __builtin_bit_cast(unsigned, x);
    unsigned r = u + 0x7FFFu + ((u >> 16) & 1u);
    return (short)(r >> 16);
}

// ---------------------------------------------------------------------------
// Kernel A: h_table[r][j] = sigmoid(lookup[idx[r]].wx[:,j] + (h0@wh)[j])
// Also emits bf16 A-fragments (16x16x32, K padded 16->32).
// ---------------------------------------------------------------------------
__global__ __launch_bounds__(256) void k_htable(
    const int* __restrict__ idx, const float* __restrict__ lookup,
    const float* __restrict__ wx, const float* __restrict__ wh,
    const float* __restrict__ h0, float* __restrict__ h_table,
    short* __restrict__ a_frag)
{
    int r = blockIdx.x * 256 + threadIdx.x;
    if (r >= NROWS) return;

    float acc[HID];
    #pragma unroll
    for (int j = 0; j < HID; ++j) acc[j] = 0.f;

    #pragma unroll
    for (int i = 0; i < HID; ++i) {
        float h0i = h0[i];
        #pragma unroll
        for (int j = 0; j < HID; ++j) acc[j] += h0i * wh[i * HID + j];
    }

    int tok = idx[r];
    const float* xrow = lookup + (long)tok * EMB;
    #pragma unroll
    for (int e = 0; e < EMB; ++e) {
        float x = xrow[e];
        #pragma unroll
        for (int j = 0; j < HID; ++j) acc[j] += x * wx[e * HID + j];
    }

    float h[HID];
    #pragma unroll
    for (int j = 0; j < HID; ++j) {
        h[j] = 1.f / (1.f + __expf(-acc[j]));
        h_table[r * HID + j] = h[j];
    }

    const int rb = r >> 4;
    const int m  = r & 15;
    short8 lo, hi, zz;
    #pragma unroll
    for (int j = 0; j < 8; ++j) {
        lo[j] = bf16_rne(h[j]);
        hi[j] = bf16_rne(h[j + 8]);
        zz[j] = 0;
    }
    short8* af = reinterpret_cast<short8*>(a_frag);
    af[rb * 64 + m]      = lo;   // lanes 0..15:  k = 0..7
    af[rb * 64 + m + 16] = hi;   // lanes 16..31: k = 8..15
    af[rb * 64 + m + 32] = zz;   // pad
    af[rb * 64 + m + 48] = zz;   // pad
}

// ---------------------------------------------------------------------------
// Kernel A2: pack Wo into bf16 B-fragments (same slot->k convention as A).
// ---------------------------------------------------------------------------
__global__ __launch_bounds__(256) void k_wpack(
    const float* __restrict__ wo, short* __restrict__ b_frag)
{
    int gid = blockIdx.x * 256 + threadIdx.x;   // 2000*64 threads
    if (gid >= NTILES * 64) return;
    const int t = gid >> 6;
    const int l = gid & 63;
    const int col = t * 16 + (l & 15);

    short8 b;
    if (l < 32) {
        const int k0 = (l >> 4) * 8;
        #pragma unroll
        for (int j = 0; j < 8; ++j)
            b[j] = bf16_rne(wo[(size_t)(k0 + j) * V_SIZE + col]);
    } else {
        #pragma unroll
        for (int j = 0; j < 8; ++j) b[j] = 0;
    }
    reinterpret_cast<short8*>(b_frag)[gid] = b;
}

// ---------------------------------------------------------------------------
// Kernel B: MFMA exp-sum — R11 mapping (12800 waves) + tile-sweep ROTATION
// (each wave starts at rb%TPW within its strip, so the 256 row-waves of a
// strip touch ~40 DIFFERENT tiles at any instant instead of the same one —
// tests the L2 same-address-hotspot hypothesis).
// XREPS=3 internal repeat (acc reset per rep, identical stores) is
// DIAGNOSTIC ONLY: makes this dispatch top the profile with full counters.
// ---------------------------------------------------------------------------
__global__ __launch_bounds__(256) void k_expsum(
    const short* __restrict__ a_frag, const short* __restrict__ b_frag,
    float* __restrict__ partial)
{
    const int lane = threadIdx.x & 63;
    const int wid  = threadIdx.x >> 6;
    const int g = blockIdx.x * 4 + wid;      // 0..12799
    const int rb = g & (NRB - 1);            // 0..255
    const int strip = g >> 8;                // 0..49

    const short8* af = reinterpret_cast<const short8*>(a_frag);
    const short8* bf = reinterpret_cast<const short8*>(b_frag);

    const short8 a = af[rb * 64 + lane];
    const f32x4 czero = {0.f, 0.f, 0.f, 0.f};
    const int t0 = strip * TPW;
    const int rot = rb % TPW;

    #pragma unroll 1
    for (int rep = 0; rep < XREPS; ++rep) {
        f32x4 acc = {0.f, 0.f, 0.f, 0.f};

        int t = t0 + rot;
        for (int i = 0; i < TPW; ++i) {
            const short8 b = bf[t * 64 + lane];
            f32x4 d = __builtin_amdgcn_mfma_f32_16x16x32_bf16(a, b, czero, 0, 0, 0);
            acc.x += __expf(d.x);
            acc.y += __expf(d.y);
            acc.z += __expf(d.z);
            acc.w += __expf(d.w);
            ++t;
            if (t == t0 + TPW) t = t0;
        }

        // reduce across the 16 column-lanes (lane&15)
        #pragma unroll
        for (int off = 1; off <= 8; off <<= 1) {
            acc.x += __shfl_xor(acc.x, off, 64);
            acc.y += __shfl_xor(acc.y, off, 64);
            acc.z += __shfl_xor(acc.z, off, 64);
            acc.w += __shfl_xor(acc.w, off, 64);
        }

        if ((lane & 15) == 0) {
            const int rbase = rb * 16 + (lane >> 4) * 4;
            float* p = partial + (size_t)strip * NROWS + rbase;
            p[0] = acc.x;
            p[1] = acc.y;
            p[2] = acc.z;
            p[3] = acc.w;
        }
    }
}

// ---------------------------------------------------------------------------
// Kernel B2: lse[r] = log( sum over 50 slots of partial[slot][r] )
// ---------------------------------------------------------------------------
__global__ __launch_bounds__(256) void k_reduce(
    const float* __restrict__ partial, float* __restrict__ lse)
{
    int r = blockIdx.x * 256 + threadIdx.x;
    if (r >= NROWS) return;
    float s = 0.f;
    #pragma unroll
    for (int k = 0; k < NSLOTS; ++k)
        s += partial[(size_t)k * NROWS + r];
    lse[r] = __logf(s);
}

// ---------------------------------------------------------------------------
// Kernel C: unchanged R9 structure (measured ~90 us @ 5.84 TB/s).
// ---------------------------------------------------------------------------
__global__ __launch_bounds__(256) void k_write(
    const float* __restrict__ h_table, const float* __restrict__ wo,
    const float* __restrict__ lse, float* __restrict__ out)
{
    const int tid = threadIdx.x;
    const int strip = blockIdx.x & (STRIPS - 1);
    const int chunk = blockIdx.x / STRIPS;
    const int v4 = strip * 256 + tid;
    const bool act = v4 < V4;
    const int r0 = chunk * ROWS_W;

    const f32x4* wo4 = reinterpret_cast<const f32x4*>(wo);
    f32x4 w[HID];
    #pragma unroll
    for (int j = 0; j < HID; ++j) {
        if (act) w[j] = wo4[j * V4 + v4];
        else     w[j] = (f32x4){0.f, 0.f, 0.f, 0.f};
    }

    f32x4* out4 = reinterpret_cast<f32x4*>(out);

    for (int rr = r0; rr < r0 + ROWS_W; rr += RGROUP) {
        f32x4 acc[RGROUP];
        #pragma unroll
        for (int i = 0; i < RGROUP; ++i) acc[i] = (f32x4){0.f, 0.f, 0.f, 0.f};

        #pragma unroll
        for (int q = 0; q < 4; ++q) {
            f32x4 h4[RGROUP];
            #pragma unroll
            for (int i = 0; i < RGROUP; ++i)
                h4[i] = *reinterpret_cast<const f32x4*>(h_table + (rr + i) * HID + q * 4);
            #pragma unroll
            for (int i = 0; i < RGROUP; ++i) {
                acc[i] += h4[i].x * w[q * 4 + 0];
                acc[i] += h4[i].y * w[q * 4 + 1];
                acc[i] += h4[i].z * w[q * 4 + 2];
                acc[i] += h4[i].w * w[q * 4 + 3];
            }
        }

        const f32x4 ls0 = *reinterpret_cast<const f32x4*>(lse + rr);
        const f32x4 ls1 = *reinterpret_cast<const f32x4*>(lse + rr + 4);

        if (act) {
            #pragma unroll
            for (int i = 0; i < RGROUP; ++i) {
                float l = (i < 4) ? ls0[i & 3] : ls1[i & 3];
                f32x4 o = acc[i] - l;
                out4[(long)(rr + i) * V4 + v4] = o;
            }
        }
    }
}

extern "C" void kernel_launch(void* const* d_in, const int* in_sizes, int n_in,
                              void* d_out, int out_size, void* d_ws, size_t ws_size,
                              hipStream_t stream) {
    const int*   idx    = (const int*)d_in[0];
    const float* lookup = (const float*)d_in[1];
    const float* wx     = (const float*)d_in[2];
    const float* wh     = (const float*)d_in[3];
    const float* wo     = (const float*)d_in[4];
    const float* h0     = (const float*)d_in[5];
    float* out = (float*)d_out;

    float* h_table = (float*)d_ws;                       // 4096*16 f32   (256 KB)
    float* lse     = h_table + NROWS * HID;              // 4096 f32
    float* partial = lse + NROWS;                        // 50*4096 f32   (800 KB)
    short* a_frag  = (short*)(partial + NSLOTS * NROWS); // 256*64*8 bf16 (256 KB)
    short* b_frag  = a_frag + NRB * 64 * 8;              // 2000*64*8 bf16 (2 MB)

    k_htable<<<NROWS / 256, 256, 0, stream>>>(idx, lookup, wx, wh, h0, h_table, a_frag);
    k_wpack<<<(NTILES * 64) / 256, 256, 0, stream>>>(wo, b_frag);
    k_expsum<<<(NRB * XSTRIPS) / 4, 256, 0, stream>>>(a_frag, b_frag, partial);
    k_reduce<<<NROWS / 256, 256, 0, stream>>>(partial, lse);
    k_write<<<STRIPS * CHUNKS, 256, 0, stream>>>(h_table, wo, lse, out);
}

// Round 14
// 162.706 us; speedup vs baseline: 1.3063x; 1.3063x over previous
//
#include <hip/hip_runtime.h>
#include <hip/hip_bf16.h>

#define V_SIZE 32000
#define SEQ 64
#define BATCH 64
#define EMB 32
#define HID 16
#define NROWS (SEQ * BATCH)   // 4096
#define V4 (V_SIZE / 4)       // 8000 float4 columns
#define STRIPS 32             // k_write: 32 strips * 256 f4-cols
#define CHUNKS 64
#define ROWS_W (NROWS / CHUNKS)   // 64 rows per chunk
#define RGROUP 8                  // rows per inner group in k_write
#define NRB (NROWS / 16)          // 256 row-blocks (MFMA M-tiles)
#define NTILES (V_SIZE / 16)      // 2000 col-tiles (MFMA N-tiles)
#define XSTRIPS 50                // expsum strips
#define TPW (NTILES / XSTRIPS)    // 40 tiles per wave
#define NSLOTS XSTRIPS

typedef float f32x4 __attribute__((ext_vector_type(4)));
typedef short short8 __attribute__((ext_vector_type(8)));

__device__ inline short bf16_rne(float x) {
    unsigned u = __builtin_bit_cast(unsigned, x);
    unsigned r = u + 0x7FFFu + ((u >> 16) & 1u);
    return (short)(r >> 16);
}

// ---------------------------------------------------------------------------
// Kernel A: h_table[r][j] = sigmoid(lookup[idx[r]].wx[:,j] + (h0@wh)[j])
// Also emits bf16 A-fragments (16x16x32, K padded 16->32).
// ---------------------------------------------------------------------------
__global__ __launch_bounds__(256) void k_htable(
    const int* __restrict__ idx, const float* __restrict__ lookup,
    const float* __restrict__ wx, const float* __restrict__ wh,
    const float* __restrict__ h0, float* __restrict__ h_table,
    short* __restrict__ a_frag)
{
    int r = blockIdx.x * 256 + threadIdx.x;
    if (r >= NROWS) return;

    float acc[HID];
    #pragma unroll
    for (int j = 0; j < HID; ++j) acc[j] = 0.f;

    #pragma unroll
    for (int i = 0; i < HID; ++i) {
        float h0i = h0[i];
        #pragma unroll
        for (int j = 0; j < HID; ++j) acc[j] += h0i * wh[i * HID + j];
    }

    int tok = idx[r];
    const float* xrow = lookup + (long)tok * EMB;
    #pragma unroll
    for (int e = 0; e < EMB; ++e) {
        float x = xrow[e];
        #pragma unroll
        for (int j = 0; j < HID; ++j) acc[j] += x * wx[e * HID + j];
    }

    float h[HID];
    #pragma unroll
    for (int j = 0; j < HID; ++j) {
        h[j] = 1.f / (1.f + __expf(-acc[j]));
        h_table[r * HID + j] = h[j];
    }

    const int rb = r >> 4;
    const int m  = r & 15;
    short8 lo, hi, zz;
    #pragma unroll
    for (int j = 0; j < 8; ++j) {
        lo[j] = bf16_rne(h[j]);
        hi[j] = bf16_rne(h[j + 8]);
        zz[j] = 0;
    }
    short8* af = reinterpret_cast<short8*>(a_frag);
    af[rb * 64 + m]      = lo;   // lanes 0..15:  k = 0..7
    af[rb * 64 + m + 16] = hi;   // lanes 16..31: k = 8..15
    af[rb * 64 + m + 32] = zz;   // pad
    af[rb * 64 + m + 48] = zz;   // pad
}

// ---------------------------------------------------------------------------
// Kernel A2: pack Wo into bf16 B-fragments (same slot->k convention as A).
// ---------------------------------------------------------------------------
__global__ __launch_bounds__(256) void k_wpack(
    const float* __restrict__ wo, short* __restrict__ b_frag)
{
    int gid = blockIdx.x * 256 + threadIdx.x;   // 2000*64 threads
    if (gid >= NTILES * 64) return;
    const int t = gid >> 6;
    const int l = gid & 63;
    const int col = t * 16 + (l & 15);

    short8 b;
    if (l < 32) {
        const int k0 = (l >> 4) * 8;
        #pragma unroll
        for (int j = 0; j < 8; ++j)
            b[j] = bf16_rne(wo[(size_t)(k0 + j) * V_SIZE + col]);
    } else {
        #pragma unroll
        for (int j = 0; j < 8; ++j) b[j] = 0;
    }
    reinterpret_cast<short8*>(b_frag)[gid] = b;
}

// ---------------------------------------------------------------------------
// Kernel B: MFMA exp-sum — rotated tile sweep (R13, halves L2 same-line
// camping) + prefetch-2 pipeline (breaks the load->mfma->exp dependence
// chain; b-load for tile i+2 issues before tile i's MFMA).
// C/D layout (m89-verified): col=lane&15, row=(lane>>4)*4+reg.
// ---------------------------------------------------------------------------
__global__ __launch_bounds__(256) void k_expsum(
    const short* __restrict__ a_frag, const short* __restrict__ b_frag,
    float* __restrict__ partial)
{
    const int lane = threadIdx.x & 63;
    const int wid  = threadIdx.x >> 6;
    const int g = blockIdx.x * 4 + wid;      // 0..12799
    const int rb = g & (NRB - 1);            // 0..255
    const int strip = g >> 8;                // 0..49

    const short8* af = reinterpret_cast<const short8*>(a_frag);
    const short8* bf = reinterpret_cast<const short8*>(b_frag);

    const short8 a = af[rb * 64 + lane];
    const f32x4 czero = {0.f, 0.f, 0.f, 0.f};
    const int t0 = strip * TPW;
    const int tend = t0 + TPW;
    const int rot = rb % TPW;

    f32x4 acc = {0.f, 0.f, 0.f, 0.f};

    int t  = t0 + rot;
    int tn = t + 1;  if (tn == tend) tn = t0;
    short8 bcur = bf[t * 64 + lane];
    short8 bnxt = bf[tn * 64 + lane];

    for (int i = 0; i < TPW; ++i) {
        int tp = tn + 1;  if (tp == tend) tp = t0;
        short8 bpre = bf[tp * 64 + lane];

        f32x4 d = __builtin_amdgcn_mfma_f32_16x16x32_bf16(a, bcur, czero, 0, 0, 0);
        acc.x += __expf(d.x);
        acc.y += __expf(d.y);
        acc.z += __expf(d.z);
        acc.w += __expf(d.w);

        bcur = bnxt;
        bnxt = bpre;
        tn = tp;
    }

    // reduce across the 16 column-lanes (lane&15)
    #pragma unroll
    for (int off = 1; off <= 8; off <<= 1) {
        acc.x += __shfl_xor(acc.x, off, 64);
        acc.y += __shfl_xor(acc.y, off, 64);
        acc.z += __shfl_xor(acc.z, off, 64);
        acc.w += __shfl_xor(acc.w, off, 64);
    }

    if ((lane & 15) == 0) {
        const int rbase = rb * 16 + (lane >> 4) * 4;
        float* p = partial + (size_t)strip * NROWS + rbase;
        p[0] = acc.x;
        p[1] = acc.y;
        p[2] = acc.z;
        p[3] = acc.w;
    }
}

// ---------------------------------------------------------------------------
// Kernel B2: lse[r] = log( sum over 50 slots of partial[slot][r] )
// ---------------------------------------------------------------------------
__global__ __launch_bounds__(256) void k_reduce(
    const float* __restrict__ partial, float* __restrict__ lse)
{
    int r = blockIdx.x * 256 + threadIdx.x;
    if (r >= NROWS) return;
    float s = 0.f;
    #pragma unroll
    for (int k = 0; k < NSLOTS; ++k)
        s += partial[(size_t)k * NROWS + r];
    lse[r] = __logf(s);
}

// ---------------------------------------------------------------------------
// Kernel C: unchanged R9 structure (measured ~90 us @ 5.84 TB/s).
// ---------------------------------------------------------------------------
__global__ __launch_bounds__(256) void k_write(
    const float* __restrict__ h_table, const float* __restrict__ wo,
    const float* __restrict__ lse, float* __restrict__ out)
{
    const int tid = threadIdx.x;
    const int strip = blockIdx.x & (STRIPS - 1);
    const int chunk = blockIdx.x / STRIPS;
    const int v4 = strip * 256 + tid;
    const bool act = v4 < V4;
    const int r0 = chunk * ROWS_W;

    const f32x4* wo4 = reinterpret_cast<const f32x4*>(wo);
    f32x4 w[HID];
    #pragma unroll
    for (int j = 0; j < HID; ++j) {
        if (act) w[j] = wo4[j * V4 + v4];
        else     w[j] = (f32x4){0.f, 0.f, 0.f, 0.f};
    }

    f32x4* out4 = reinterpret_cast<f32x4*>(out);

    for (int rr = r0; rr < r0 + ROWS_W; rr += RGROUP) {
        f32x4 acc[RGROUP];
        #pragma unroll
        for (int i = 0; i < RGROUP; ++i) acc[i] = (f32x4){0.f, 0.f, 0.f, 0.f};

        #pragma unroll
        for (int q = 0; q < 4; ++q) {
            f32x4 h4[RGROUP];
            #pragma unroll
            for (int i = 0; i < RGROUP; ++i)
                h4[i] = *reinterpret_cast<const f32x4*>(h_table + (rr + i) * HID + q * 4);
            #pragma unroll
            for (int i = 0; i < RGROUP; ++i) {
                acc[i] += h4[i].x * w[q * 4 + 0];
                acc[i] += h4[i].y * w[q * 4 + 1];
                acc[i] += h4[i].z * w[q * 4 + 2];
                acc[i] += h4[i].w * w[q * 4 + 3];
            }
        }

        const f32x4 ls0 = *reinterpret_cast<const f32x4*>(lse + rr);
        const f32x4 ls1 = *reinterpret_cast<const f32x4*>(lse + rr + 4);

        if (act) {
            #pragma unroll
            for (int i = 0; i < RGROUP; ++i) {
                float l = (i < 4) ? ls0[i & 3] : ls1[i & 3];
                f32x4 o = acc[i] - l;
                out4[(long)(rr + i) * V4 + v4] = o;
            }
        }
    }
}

extern "C" void kernel_launch(void* const* d_in, const int* in_sizes, int n_in,
                              void* d_out, int out_size, void* d_ws, size_t ws_size,
                              hipStream_t stream) {
    const int*   idx    = (const int*)d_in[0];
    const float* lookup = (const float*)d_in[1];
    const float* wx     = (const float*)d_in[2];
    const float* wh     = (const float*)d_in[3];
    const float* wo     = (const float*)d_in[4];
    const float* h0     = (const float*)d_in[5];
    float* out = (float*)d_out;

    float* h_table = (float*)d_ws;                       // 4096*16 f32   (256 KB)
    float* lse     = h_table + NROWS * HID;              // 4096 f32
    float* partial = lse + NROWS;                        // 50*4096 f32   (800 KB)
    short* a_frag  = (short*)(partial + NSLOTS * NROWS); // 256*64*8 bf16 (256 KB)
    short* b_frag  = a_frag + NRB * 64 * 8;              // 2000*64*8 bf16 (2 MB)

    k_htable<<<NROWS / 256, 256, 0, stream>>>(idx, lookup, wx, wh, h0, h_table, a_frag);
    k_wpack<<<(NTILES * 64) / 256, 256, 0, stream>>>(wo, b_frag);
    k_expsum<<<(NRB * XSTRIPS) / 4, 256, 0, stream>>>(a_frag, b_frag, partial);
    k_reduce<<<NROWS / 256, 256, 0, stream>>>(partial, lse);
    k_write<<<STRIPS * CHUNKS, 256, 0, stream>>>(h_table, wo, lse, out);
}

// Round 15
// 160.974 us; speedup vs baseline: 1.3204x; 1.0108x over previous
//
#include <hip/hip_runtime.h>
#include <hip/hip_bf16.h>

#define V_SIZE 32000
#define SEQ 64
#define BATCH 64
#define EMB 32
#define HID 16
#define NROWS (SEQ * BATCH)   // 4096
#define V4 (V_SIZE / 4)       // 8000 float4 columns
#define STRIPS 32             // k_write: 32 strips * 256 f4-cols
#define CHUNKS 64
#define ROWS_W (NROWS / CHUNKS)   // 64 rows per chunk
#define RGROUP 8                  // rows per inner group in k_write
#define NRB (NROWS / 16)          // 256 row-blocks (MFMA M-tiles)
#define NTILES (V_SIZE / 16)      // 2000 col-tiles (MFMA N-tiles)
#define RBW 2                     // row-blocks per wave (b-frag reuse)
#define NRG (NRB / RBW)           // 128 row-groups
#define XSTRIPS 50                // expsum strips
#define TPW (NTILES / XSTRIPS)    // 40 tiles per wave
#define NSLOTS XSTRIPS
#define HT_BLOCKS (NROWS / 256)       // 16
#define WP_BLOCKS (NTILES * 64 / 256) // 500

typedef float f32x4 __attribute__((ext_vector_type(4)));
typedef short short8 __attribute__((ext_vector_type(8)));

__device__ inline short bf16_rne(float x) {
    unsigned u = __builtin_bit_cast(unsigned, x);
    unsigned r = u + 0x7FFFu + ((u >> 16) & 1u);
    return (short)(r >> 16);
}

// ---------------------------------------------------------------------------
// Kernel A (merged): blocks 0..15 build h_table + A-frags; blocks 16..515
// pack Wo into bf16 B-frags. Disjoint outputs -> deterministic.
// ---------------------------------------------------------------------------
__global__ __launch_bounds__(256) void k_prep(
    const int* __restrict__ idx, const float* __restrict__ lookup,
    const float* __restrict__ wx, const float* __restrict__ wh,
    const float* __restrict__ h0, const float* __restrict__ wo,
    float* __restrict__ h_table, short* __restrict__ a_frag,
    short* __restrict__ b_frag)
{
    if (blockIdx.x < HT_BLOCKS) {
        int r = blockIdx.x * 256 + threadIdx.x;

        float acc[HID];
        #pragma unroll
        for (int j = 0; j < HID; ++j) acc[j] = 0.f;

        #pragma unroll
        for (int i = 0; i < HID; ++i) {
            float h0i = h0[i];
            #pragma unroll
            for (int j = 0; j < HID; ++j) acc[j] += h0i * wh[i * HID + j];
        }

        int tok = idx[r];
        const float* xrow = lookup + (long)tok * EMB;
        #pragma unroll
        for (int e = 0; e < EMB; ++e) {
            float x = xrow[e];
            #pragma unroll
            for (int j = 0; j < HID; ++j) acc[j] += x * wx[e * HID + j];
        }

        float h[HID];
        #pragma unroll
        for (int j = 0; j < HID; ++j) {
            h[j] = 1.f / (1.f + __expf(-acc[j]));
            h_table[r * HID + j] = h[j];
        }

        const int rb = r >> 4;
        const int m  = r & 15;
        short8 lo, hi, zz;
        #pragma unroll
        for (int j = 0; j < 8; ++j) {
            lo[j] = bf16_rne(h[j]);
            hi[j] = bf16_rne(h[j + 8]);
            zz[j] = 0;
        }
        short8* af = reinterpret_cast<short8*>(a_frag);
        af[rb * 64 + m]      = lo;   // lanes 0..15:  k = 0..7
        af[rb * 64 + m + 16] = hi;   // lanes 16..31: k = 8..15
        af[rb * 64 + m + 32] = zz;   // pad
        af[rb * 64 + m + 48] = zz;   // pad
    } else {
        int gid = (blockIdx.x - HT_BLOCKS) * 256 + threadIdx.x;  // 0..127999
        const int t = gid >> 6;
        const int l = gid & 63;
        const int col = t * 16 + (l & 15);

        short8 b;
        if (l < 32) {
            const int k0 = (l >> 4) * 8;
            #pragma unroll
            for (int j = 0; j < 8; ++j)
                b[j] = bf16_rne(wo[(size_t)(k0 + j) * V_SIZE + col]);
        } else {
            #pragma unroll
            for (int j = 0; j < 8; ++j) b[j] = 0;
        }
        reinterpret_cast<short8*>(b_frag)[gid] = b;
    }
}

// ---------------------------------------------------------------------------
// Kernel B: MFMA exp-sum — RBW=2 (one b-frag load feeds 2 MFMAs; L2 traffic
// 512 -> 256 MB) + rotation (kills R12's lockstep same-line camping) +
// prefetch-2 (b-load for tile i+2 issues before tile i's MFMA).
// C/D layout (m89-verified): col=lane&15, row=(lane>>4)*4+reg.
// ---------------------------------------------------------------------------
__global__ __launch_bounds__(256) void k_expsum(
    const short* __restrict__ a_frag, const short* __restrict__ b_frag,
    float* __restrict__ partial)
{
    const int lane = threadIdx.x & 63;
    const int wid  = threadIdx.x >> 6;
    const int g = blockIdx.x * 4 + wid;      // 0..6399
    const int rbg = g & (NRG - 1);           // 0..127
    const int strip = g >> 7;                // 0..49

    const short8* af = reinterpret_cast<const short8*>(a_frag);
    const short8* bf = reinterpret_cast<const short8*>(b_frag);

    short8 a[RBW];
    #pragma unroll
    for (int i = 0; i < RBW; ++i)
        a[i] = af[(rbg * RBW + i) * 64 + lane];

    const f32x4 czero = {0.f, 0.f, 0.f, 0.f};
    const int t0 = strip * TPW;
    const int tend = t0 + TPW;
    const int rot = rbg % TPW;

    f32x4 acc[RBW];
    #pragma unroll
    for (int i = 0; i < RBW; ++i) acc[i] = (f32x4){0.f, 0.f, 0.f, 0.f};

    int t  = t0 + rot;
    int tn = t + 1;  if (tn == tend) tn = t0;
    short8 bcur = bf[t * 64 + lane];
    short8 bnxt = bf[tn * 64 + lane];

    for (int i = 0; i < TPW; ++i) {
        int tp = tn + 1;  if (tp == tend) tp = t0;
        short8 bpre = bf[tp * 64 + lane];

        f32x4 d[RBW];
        #pragma unroll
        for (int k = 0; k < RBW; ++k)
            d[k] = __builtin_amdgcn_mfma_f32_16x16x32_bf16(a[k], bcur, czero, 0, 0, 0);

        #pragma unroll
        for (int k = 0; k < RBW; ++k) {
            acc[k].x += __expf(d[k].x);
            acc[k].y += __expf(d[k].y);
            acc[k].z += __expf(d[k].z);
            acc[k].w += __expf(d[k].w);
        }

        bcur = bnxt;
        bnxt = bpre;
        tn = tp;
    }

    // reduce across the 16 column-lanes (lane&15)
    #pragma unroll
    for (int off = 1; off <= 8; off <<= 1) {
        #pragma unroll
        for (int k = 0; k < RBW; ++k) {
            acc[k].x += __shfl_xor(acc[k].x, off, 64);
            acc[k].y += __shfl_xor(acc[k].y, off, 64);
            acc[k].z += __shfl_xor(acc[k].z, off, 64);
            acc[k].w += __shfl_xor(acc[k].w, off, 64);
        }
    }

    if ((lane & 15) == 0) {
        #pragma unroll
        for (int k = 0; k < RBW; ++k) {
            const int rbase = (rbg * RBW + k) * 16 + (lane >> 4) * 4;
            float* p = partial + (size_t)strip * NROWS + rbase;
            p[0] = acc[k].x;
            p[1] = acc[k].y;
            p[2] = acc[k].z;
            p[3] = acc[k].w;
        }
    }
}

// ---------------------------------------------------------------------------
// Kernel B2: lse[r] = log( sum over 50 slots of partial[slot][r] )
// ---------------------------------------------------------------------------
__global__ __launch_bounds__(256) void k_reduce(
    const float* __restrict__ partial, float* __restrict__ lse)
{
    int r = blockIdx.x * 256 + threadIdx.x;
    if (r >= NROWS) return;
    float s = 0.f;
    #pragma unroll
    for (int k = 0; k < NSLOTS; ++k)
        s += partial[(size_t)k * NROWS + r];
    lse[r] = __logf(s);
}

// ---------------------------------------------------------------------------
// Kernel C: unchanged R9 structure (measured ~90 us @ 5.84 TB/s).
// ---------------------------------------------------------------------------
__global__ __launch_bounds__(256) void k_write(
    const float* __restrict__ h_table, const float* __restrict__ wo,
    const float* __restrict__ lse, float* __restrict__ out)
{
    const int tid = threadIdx.x;
    const int strip = blockIdx.x & (STRIPS - 1);
    const int chunk = blockIdx.x / STRIPS;
    const int v4 = strip * 256 + tid;
    const bool act = v4 < V4;
    const int r0 = chunk * ROWS_W;

    const f32x4* wo4 = reinterpret_cast<const f32x4*>(wo);
    f32x4 w[HID];
    #pragma unroll
    for (int j = 0; j < HID; ++j) {
        if (act) w[j] = wo4[j * V4 + v4];
        else     w[j] = (f32x4){0.f, 0.f, 0.f, 0.f};
    }

    f32x4* out4 = reinterpret_cast<f32x4*>(out);

    for (int rr = r0; rr < r0 + ROWS_W; rr += RGROUP) {
        f32x4 acc[RGROUP];
        #pragma unroll
        for (int i = 0; i < RGROUP; ++i) acc[i] = (f32x4){0.f, 0.f, 0.f, 0.f};

        #pragma unroll
        for (int q = 0; q < 4; ++q) {
            f32x4 h4[RGROUP];
            #pragma unroll
            for (int i = 0; i < RGROUP; ++i)
                h4[i] = *reinterpret_cast<const f32x4*>(h_table + (rr + i) * HID + q * 4);
            #pragma unroll
            for (int i = 0; i < RGROUP; ++i) {
                acc[i] += h4[i].x * w[q * 4 + 0];
                acc[i] += h4[i].y * w[q * 4 + 1];
                acc[i] += h4[i].z * w[q * 4 + 2];
                acc[i] += h4[i].w * w[q * 4 + 3];
            }
        }

        const f32x4 ls0 = *reinterpret_cast<const f32x4*>(lse + rr);
        const f32x4 ls1 = *reinterpret_cast<const f32x4*>(lse + rr + 4);

        if (act) {
            #pragma unroll
            for (int i = 0; i < RGROUP; ++i) {
                float l = (i < 4) ? ls0[i & 3] : ls1[i & 3];
                f32x4 o = acc[i] - l;
                out4[(long)(rr + i) * V4 + v4] = o;
            }
        }
    }
}

extern "C" void kernel_launch(void* const* d_in, const int* in_sizes, int n_in,
                              void* d_out, int out_size, void* d_ws, size_t ws_size,
                              hipStream_t stream) {
    const int*   idx    = (const int*)d_in[0];
    const float* lookup = (const float*)d_in[1];
    const float* wx     = (const float*)d_in[2];
    const float* wh     = (const float*)d_in[3];
    const float* wo     = (const float*)d_in[4];
    const float* h0     = (const float*)d_in[5];
    float* out = (float*)d_out;

    float* h_table = (float*)d_ws;                       // 4096*16 f32   (256 KB)
    float* lse     = h_table + NROWS * HID;              // 4096 f32
    float* partial = lse + NROWS;                        // 50*4096 f32   (800 KB)
    short* a_frag  = (short*)(partial + NSLOTS * NROWS); // 256*64*8 bf16 (256 KB)
    short* b_frag  = a_frag + NRB * 64 * 8;              // 2000*64*8 bf16 (2 MB)

    k_prep<<<HT_BLOCKS + WP_BLOCKS, 256, 0, stream>>>(idx, lookup, wx, wh, h0, wo,
                                                      h_table, a_frag, b_frag);
    k_expsum<<<(NRG * XSTRIPS) / 4, 256, 0, stream>>>(a_frag, b_frag, partial);
    k_reduce<<<NROWS / 256, 256, 0, stream>>>(partial, lse);
    k_write<<<STRIPS * CHUNKS, 256, 0, stream>>>(h_table, wo, lse, out);
}

// Round 16
// 157.901 us; speedup vs baseline: 1.3461x; 1.0195x over previous
//
#include <hip/hip_runtime.h>
#include <hip/hip_bf16.h>

#define V_SIZE 32000
#define SEQ 64
#define BATCH 64
#define EMB 32
#define HID 16
#define NROWS (SEQ * BATCH)   // 4096
#define V4 (V_SIZE / 4)       // 8000 float4 columns
#define STRIPS 32             // k_write: 32 strips * 256 f4-cols
#define CHUNKS 64
#define ROWS_W (NROWS / CHUNKS)   // 64 rows per chunk
#define RGROUP 8                  // rows per inner group in k_write
#define NRB (NROWS / 16)          // 256 row-blocks (MFMA M-tiles)
#define NTILES (V_SIZE / 16)      // 2000 col-tiles (MFMA N-tiles)
#define RBW 4                     // row-blocks per wave (b-frag reuse)
#define NRG (NRB / RBW)           // 64 row-groups
#define XSTRIPS 50                // expsum strips
#define TPW (NTILES / XSTRIPS)    // 40 tiles per wave
#define NSLOTS XSTRIPS
#define HT_BLOCKS (NROWS / 256)       // 16
#define WP_BLOCKS (NTILES * 64 / 256) // 500

typedef float f32x4 __attribute__((ext_vector_type(4)));
typedef short short8 __attribute__((ext_vector_type(8)));

__device__ inline short bf16_rne(float x) {
    unsigned u = __builtin_bit_cast(unsigned, x);
    unsigned r = u + 0x7FFFu + ((u >> 16) & 1u);
    return (short)(r >> 16);
}

// ---------------------------------------------------------------------------
// Kernel A (merged): blocks 0..15 build h_table + A-frags; blocks 16..515
// pack Wo into bf16 B-frags. Disjoint outputs -> deterministic.
// ---------------------------------------------------------------------------
__global__ __launch_bounds__(256) void k_prep(
    const int* __restrict__ idx, const float* __restrict__ lookup,
    const float* __restrict__ wx, const float* __restrict__ wh,
    const float* __restrict__ h0, const float* __restrict__ wo,
    float* __restrict__ h_table, short* __restrict__ a_frag,
    short* __restrict__ b_frag)
{
    if (blockIdx.x < HT_BLOCKS) {
        int r = blockIdx.x * 256 + threadIdx.x;

        float acc[HID];
        #pragma unroll
        for (int j = 0; j < HID; ++j) acc[j] = 0.f;

        #pragma unroll
        for (int i = 0; i < HID; ++i) {
            float h0i = h0[i];
            #pragma unroll
            for (int j = 0; j < HID; ++j) acc[j] += h0i * wh[i * HID + j];
        }

        int tok = idx[r];
        const float* xrow = lookup + (long)tok * EMB;
        #pragma unroll
        for (int e = 0; e < EMB; ++e) {
            float x = xrow[e];
            #pragma unroll
            for (int j = 0; j < HID; ++j) acc[j] += x * wx[e * HID + j];
        }

        float h[HID];
        #pragma unroll
        for (int j = 0; j < HID; ++j) {
            h[j] = 1.f / (1.f + __expf(-acc[j]));
            h_table[r * HID + j] = h[j];
        }

        const int rb = r >> 4;
        const int m  = r & 15;
        short8 lo, hi, zz;
        #pragma unroll
        for (int j = 0; j < 8; ++j) {
            lo[j] = bf16_rne(h[j]);
            hi[j] = bf16_rne(h[j + 8]);
            zz[j] = 0;
        }
        short8* af = reinterpret_cast<short8*>(a_frag);
        af[rb * 64 + m]      = lo;   // lanes 0..15:  k = 0..7
        af[rb * 64 + m + 16] = hi;   // lanes 16..31: k = 8..15
        af[rb * 64 + m + 32] = zz;   // pad
        af[rb * 64 + m + 48] = zz;   // pad
    } else {
        int gid = (blockIdx.x - HT_BLOCKS) * 256 + threadIdx.x;  // 0..127999
        const int t = gid >> 6;
        const int l = gid & 63;
        const int col = t * 16 + (l & 15);

        short8 b;
        if (l < 32) {
            const int k0 = (l >> 4) * 8;
            #pragma unroll
            for (int j = 0; j < 8; ++j)
                b[j] = bf16_rne(wo[(size_t)(k0 + j) * V_SIZE + col]);
        } else {
            #pragma unroll
            for (int j = 0; j < 8; ++j) b[j] = 0;
        }
        reinterpret_cast<short8*>(b_frag)[gid] = b;
    }
}

// ---------------------------------------------------------------------------
// Kernel B: MFMA exp-sum — RBW=4 (one b-frag load feeds 4 MFMAs; L2 traffic
// 128 MB) + rotation (prevents R12's lockstep same-line camping) +
// prefetch-2. 3200 waves = 12.5/CU.
// C/D layout (m89-verified): col=lane&15, row=(lane>>4)*4+reg.
// ---------------------------------------------------------------------------
__global__ __launch_bounds__(256) void k_expsum(
    const short* __restrict__ a_frag, const short* __restrict__ b_frag,
    float* __restrict__ partial)
{
    const int lane = threadIdx.x & 63;
    const int wid  = threadIdx.x >> 6;
    const int g = blockIdx.x * 4 + wid;      // 0..3199
    const int rbg = g & (NRG - 1);           // 0..63
    const int strip = g >> 6;                // 0..49

    const short8* af = reinterpret_cast<const short8*>(a_frag);
    const short8* bf = reinterpret_cast<const short8*>(b_frag);

    short8 a[RBW];
    #pragma unroll
    for (int i = 0; i < RBW; ++i)
        a[i] = af[(rbg * RBW + i) * 64 + lane];

    const f32x4 czero = {0.f, 0.f, 0.f, 0.f};
    const int t0 = strip * TPW;
    const int tend = t0 + TPW;
    const int rot = rbg % TPW;

    f32x4 acc[RBW];
    #pragma unroll
    for (int i = 0; i < RBW; ++i) acc[i] = (f32x4){0.f, 0.f, 0.f, 0.f};

    int t  = t0 + rot;
    int tn = t + 1;  if (tn == tend) tn = t0;
    short8 bcur = bf[t * 64 + lane];
    short8 bnxt = bf[tn * 64 + lane];

    for (int i = 0; i < TPW; ++i) {
        int tp = tn + 1;  if (tp == tend) tp = t0;
        short8 bpre = bf[tp * 64 + lane];

        f32x4 d[RBW];
        #pragma unroll
        for (int k = 0; k < RBW; ++k)
            d[k] = __builtin_amdgcn_mfma_f32_16x16x32_bf16(a[k], bcur, czero, 0, 0, 0);

        #pragma unroll
        for (int k = 0; k < RBW; ++k) {
            acc[k].x += __expf(d[k].x);
            acc[k].y += __expf(d[k].y);
            acc[k].z += __expf(d[k].z);
            acc[k].w += __expf(d[k].w);
        }

        bcur = bnxt;
        bnxt = bpre;
        tn = tp;
    }

    // reduce across the 16 column-lanes (lane&15)
    #pragma unroll
    for (int off = 1; off <= 8; off <<= 1) {
        #pragma unroll
        for (int k = 0; k < RBW; ++k) {
            acc[k].x += __shfl_xor(acc[k].x, off, 64);
            acc[k].y += __shfl_xor(acc[k].y, off, 64);
            acc[k].z += __shfl_xor(acc[k].z, off, 64);
            acc[k].w += __shfl_xor(acc[k].w, off, 64);
        }
    }

    if ((lane & 15) == 0) {
        #pragma unroll
        for (int k = 0; k < RBW; ++k) {
            const int rbase = (rbg * RBW + k) * 16 + (lane >> 4) * 4;
            float* p = partial + (size_t)strip * NROWS + rbase;
            p[0] = acc[k].x;
            p[1] = acc[k].y;
            p[2] = acc[k].z;
            p[3] = acc[k].w;
        }
    }
}

// ---------------------------------------------------------------------------
// Kernel C: k_write with fused lse head (k_reduce eliminated).
// Head: threads t<64 compute lse for the block's 64 rows from the 50 partial
// slots (fixed order -> deterministic; 32x redundant across strip-blocks,
// 26 MB total L2 reads). Body: unchanged R9 structure (~90 us @ 5.84 TB/s).
// ---------------------------------------------------------------------------
__global__ __launch_bounds__(256) void k_write(
    const float* __restrict__ h_table, const float* __restrict__ wo,
    const float* __restrict__ partial, float* __restrict__ out)
{
    const int tid = threadIdx.x;
    const int strip = blockIdx.x & (STRIPS - 1);
    const int chunk = blockIdx.x / STRIPS;
    const int v4 = strip * 256 + tid;
    const bool act = v4 < V4;
    const int r0 = chunk * ROWS_W;

    __shared__ float lse_s[ROWS_W];
    if (tid < ROWS_W) {
        float s = 0.f;
        #pragma unroll
        for (int k = 0; k < NSLOTS; ++k)
            s += partial[(size_t)k * NROWS + r0 + tid];
        lse_s[tid] = __logf(s);
    }

    const f32x4* wo4 = reinterpret_cast<const f32x4*>(wo);
    f32x4 w[HID];
    #pragma unroll
    for (int j = 0; j < HID; ++j) {
        if (act) w[j] = wo4[j * V4 + v4];
        else     w[j] = (f32x4){0.f, 0.f, 0.f, 0.f};
    }

    __syncthreads();

    f32x4* out4 = reinterpret_cast<f32x4*>(out);

    for (int rr = r0; rr < r0 + ROWS_W; rr += RGROUP) {
        f32x4 acc[RGROUP];
        #pragma unroll
        for (int i = 0; i < RGROUP; ++i) acc[i] = (f32x4){0.f, 0.f, 0.f, 0.f};

        #pragma unroll
        for (int q = 0; q < 4; ++q) {
            f32x4 h4[RGROUP];
            #pragma unroll
            for (int i = 0; i < RGROUP; ++i)
                h4[i] = *reinterpret_cast<const f32x4*>(h_table + (rr + i) * HID + q * 4);
            #pragma unroll
            for (int i = 0; i < RGROUP; ++i) {
                acc[i] += h4[i].x * w[q * 4 + 0];
                acc[i] += h4[i].y * w[q * 4 + 1];
                acc[i] += h4[i].z * w[q * 4 + 2];
                acc[i] += h4[i].w * w[q * 4 + 3];
            }
        }

        if (act) {
            #pragma unroll
            for (int i = 0; i < RGROUP; ++i) {
                float l = lse_s[rr - r0 + i];
                f32x4 o = acc[i] - l;
                out4[(long)(rr + i) * V4 + v4] = o;
            }
        }
    }
}

extern "C" void kernel_launch(void* const* d_in, const int* in_sizes, int n_in,
                              void* d_out, int out_size, void* d_ws, size_t ws_size,
                              hipStream_t stream) {
    const int*   idx    = (const int*)d_in[0];
    const float* lookup = (const float*)d_in[1];
    const float* wx     = (const float*)d_in[2];
    const float* wh     = (const float*)d_in[3];
    const float* wo     = (const float*)d_in[4];
    const float* h0     = (const float*)d_in[5];
    float* out = (float*)d_out;

    float* h_table = (float*)d_ws;                       // 4096*16 f32   (256 KB)
    float* partial = h_table + NROWS * HID;              // 50*4096 f32   (800 KB)
    short* a_frag  = (short*)(partial + NSLOTS * NROWS); // 256*64*8 bf16 (256 KB)
    short* b_frag  = a_frag + NRB * 64 * 8;              // 2000*64*8 bf16 (2 MB)

    k_prep<<<HT_BLOCKS + WP_BLOCKS, 256, 0, stream>>>(idx, lookup, wx, wh, h0, wo,
                                                      h_table, a_frag, b_frag);
    k_expsum<<<(NRG * XSTRIPS) / 4, 256, 0, stream>>>(a_frag, b_frag, partial);
    k_write<<<STRIPS * CHUNKS, 256, 0, stream>>>(h_table, wo, partial, out);
}